// Round 10
// baseline (4571.280 us; speedup 1.0000x reference)
//
#include <hip/hip_runtime.h>

typedef _Float16 half_t;
typedef _Float16 half2_t __attribute__((ext_vector_type(2)));
typedef _Float16 half8_t __attribute__((ext_vector_type(8)));
typedef float    f32x4   __attribute__((ext_vector_type(4)));
typedef unsigned int       u32;
typedef u32      u32x4   __attribute__((ext_vector_type(4)));

#define BB  32      // batch (chains)
#define TT  2048    // seq len
#define HH  256     // hidden = input dim
#define G3  768     // 3*H
#define TBS 64      // timesteps per G-block
#define GCH 4       // gate prefetch chunk in R (keeps VGPRs <= 256)

// R10: protocol elimination. The 4-stage UC-flag pipeline's per-chunk cost
// (~3.7 us beyond model) resisted 5 rounds of targeted fixes (LDS conflicts,
// MFMA, relaxed atomics, slack tuning) — every fix verified in counters, none
// moved cadence. xg0 = Wih0@x has NO recurrence dep; xg1 = Wih1@h0 needs only
// the finished layer-0 sequence. So: 4 protocol-free launches per T-segment:
//   G0 (bulk GEMM xg0, full chip) -> R0 (layer-0 recurrence, 32 independent
//   blocks) -> G1 (bulk GEMM xg1 from h0) -> R1 (layer-1 recurrence -> out).
// Cross-kernel visibility via stream order; zero flags/UC/drains/polls.
// Segment length adapts to ws_size (f32 gates preferred, f16 fallback).

__device__ __forceinline__ half2_t f2h2(float a, float b) {
  half2_t r; r.x = (half_t)a; r.y = (half_t)b; return r;
}
__device__ __forceinline__ float sigm(float v) {
  return __builtin_amdgcn_rcpf(1.f + __builtin_amdgcn_exp2f(v * -1.4426950408889634f));
}
__device__ __forceinline__ float tanh_fast(float v) {
  return 1.f - 2.f * __builtin_amdgcn_rcpf(1.f + __builtin_amdgcn_exp2f(v * 2.8853900817779268f));
}
// LDS-visibility barrier WITHOUT vmcnt(0): global stores stay in flight.
__device__ __forceinline__ void barrier_lds() {
  asm volatile("s_waitcnt lgkmcnt(0)" ::: "memory");
  __builtin_amdgcn_s_barrier();
  asm volatile("" ::: "memory");
}

// Weight fragments (proven in R7-R9): lane holds W[tt*128 + j0][kk*32+g4*8+j],
// j=0..7, as MFMA B-operand; D col = lane&15 -> per-lane output ownership.
__device__ __forceinline__ void load_wf(const float* __restrict__ Wm, int j0, int g4,
                                        u32x4 (&wf)[6][8]) {
#pragma unroll
  for (int tt = 0; tt < 6; ++tt) {
    const int row = tt * 128 + j0;
#pragma unroll
    for (int kk = 0; kk < 8; ++kk) {
      const float4* p = (const float4*)(Wm + (size_t)row * HH + kk * 32 + g4 * 8);
      float4 qa = p[0], qb = p[1];
      u32x4 v;
      v.x = __builtin_bit_cast(u32, f2h2(qa.x, qa.y));
      v.y = __builtin_bit_cast(u32, f2h2(qa.z, qa.w));
      v.z = __builtin_bit_cast(u32, f2h2(qb.x, qb.y));
      v.w = __builtin_bit_cast(u32, f2h2(qb.z, qb.w));
      wf[tt][kk] = v;
    }
  }
#pragma unroll
  for (int tt = 0; tt < 6; ++tt)
#pragma unroll
    for (int kk = 0; kk < 8; ++kk)
      asm volatile("" : "+v"(wf[tt][kk]));   // pin: no remat inside loops
}

// 48 MFMA: broadcast-A (all M rows = v), 6 N-tiles x 8 K-steps.
__device__ __forceinline__ void mfma48(const half2_t* __restrict__ hslot, int g4,
                                       const u32x4 (&wf)[6][8], f32x4 (&acc)[6]) {
  const float4* ab = (const float4*)hslot;
#pragma unroll
  for (int kk = 0; kk < 8; ++kk) {
    half8_t af = __builtin_bit_cast(half8_t, ab[kk * 4 + g4]);  // v[kk*32+g4*8 ..+8)
#pragma unroll
    for (int tt = 0; tt < 6; ++tt)
      acc[tt] = __builtin_amdgcn_mfma_f32_16x16x32_f16(
          af, __builtin_bit_cast(half8_t, wf[tt][kk]), acc[tt], 0, 0, 0);
  }
}

// ---------- G: xg[c][t][0:768] = Wih @ v_t + bih  (v = x or h0seg) ----------
// grid = 32 chains * (seg/TBS). No inter-wave deps except LDS staging barrier.
template <typename XG>
__global__ __launch_bounds__(512) __attribute__((amdgpu_waves_per_eu(2, 2)))
void g_xg(const float* __restrict__ xsrc,   // layer0: x base [BB][TT][HH] f32, else null
          const half_t* __restrict__ hsrc,  // layer1: hseg [BB][seg][HH] f16, else null
          const float* __restrict__ Wm,     // Wih + l*G3*HH
          const float* __restrict__ bv,     // bih + l*G3
          XG* __restrict__ xg,              // [BB][seg][G3]
          int t0, int seg, int tbs)
{
  const int chain = blockIdx.x & 31;
  const int tb    = blockIdx.x >> 5;
  const int tid   = threadIdx.x;
  const int wv = tid >> 6, lane = tid & 63, lr = lane & 15, g4 = lane >> 4;
  const int j0 = wv * 16 + lr;
  const bool act = (g4 < 2);
  const int idx = g4 * 128 + j0;

  u32x4 wf[6][8];
  load_wf(Wm, j0, g4, wf);
  float b0 = 0.f, b1 = 0.f, b2 = 0.f;
  if (act) { b0 = bv[idx]; b1 = bv[256 + idx]; b2 = bv[512 + idx]; }

  __shared__ __align__(16) half2_t hb[2][128];
  const int ts = tb * tbs, te = ts + tbs;   // tbs divides seg by construction

  // stage step ts
  if (tid < 128) {
    if (xsrc) {
      float2 v = ((const float2*)(xsrc + (size_t)(chain * TT + t0 + ts) * HH))[tid];
      hb[ts & 1][tid] = f2h2(v.x, v.y);
    } else {
      u32 v = ((const u32*)(hsrc + (size_t)(chain * seg + ts) * HH))[tid];
      hb[ts & 1][tid] = __builtin_bit_cast(half2_t, v);
    }
  }
  __syncthreads();

  for (int t = ts; t < te; ++t) {
    // stage t+1 into the other slot (overlaps MFMA)
    if (tid < 128 && t + 1 < te) {
      if (xsrc) {
        float2 v = ((const float2*)(xsrc + (size_t)(chain * TT + t0 + t + 1) * HH))[tid];
        hb[(t + 1) & 1][tid] = f2h2(v.x, v.y);
      } else {
        u32 v = ((const u32*)(hsrc + (size_t)(chain * seg + t + 1) * HH))[tid];
        hb[(t + 1) & 1][tid] = __builtin_bit_cast(half2_t, v);
      }
    }
    f32x4 acc[6];
#pragma unroll
    for (int tt = 0; tt < 6; ++tt) acc[tt] = (f32x4){0.f, 0.f, 0.f, 0.f};
    mfma48(&hb[t & 1][0], g4, wf, acc);
    if (act) {
      XG* o = xg + ((size_t)chain * seg + t) * G3;
      o[idx]       = (XG)(acc[g4 ? 1 : 0][0] + b0);
      o[256 + idx] = (XG)(acc[g4 ? 3 : 2][0] + b1);
      o[512 + idx] = (XG)(acc[g4 ? 5 : 4][0] + b2);
    }
    barrier_lds();   // staging of t+1 visible; slot t&1 free for t+2's stage
  }
}

// ---------- R: GRU cell recurrence for one layer; 32 independent blocks ----------
template <typename XG>
__global__ __launch_bounds__(512) __attribute__((amdgpu_waves_per_eu(2, 2)))
void r_cell(const XG* __restrict__ xg,      // [BB][seg][G3] precomputed gates
            const float* __restrict__ Wm,   // Whh + l*G3*HH
            const float* __restrict__ bv,   // bhh + l*G3
            half_t* __restrict__ hseq,      // layer0: h out [BB][seg][HH] f16, else null
            float* __restrict__ outp,       // layer1: out [BB][TT][HH] f32, else null
            float* __restrict__ carry,      // [BB][HH] f32 hidden-state carry
            int t0, int seg)
{
  const int chain = blockIdx.x;
  const int tid   = threadIdx.x;
  const int wv = tid >> 6, lane = tid & 63, lr = lane & 15, g4 = lane >> 4;
  const int j0 = wv * 16 + lr;
  const bool act = (g4 < 2);
  const int idx = g4 * 128 + j0;

  u32x4 wf[6][8];
  load_wf(Wm, j0, g4, wf);
  float bR = 0.f, bZ = 0.f, bN = 0.f;
  if (act) { bR = bv[idx]; bZ = bv[256 + idx]; bN = bv[512 + idx]; }

  __shared__ __align__(16) half2_t hb[2][128];
  float hprev = 0.f;
  if (act) {
    hprev = carry[chain * HH + idx];
    ((half_t*)&hb[0][0])[idx] = (half_t)hprev;   // 256 act lanes cover all idx
  }
  __syncthreads();

  for (int ck = 0; ck < seg; ck += GCH) {
    // prefetch GCH steps of gates (plain cached loads; hidden under MFMA)
    float xr[GCH], xz[GCH], xn[GCH];
    if (act) {
#pragma unroll
      for (int s8 = 0; s8 < GCH; ++s8) {
        const XG* q = xg + ((size_t)chain * seg + ck + s8) * G3;
        xr[s8] = (float)q[idx];
        xz[s8] = (float)q[256 + idx];
        xn[s8] = (float)q[512 + idx];
      }
    }
#pragma unroll
    for (int s8 = 0; s8 < GCH; ++s8) {
      const int s = ck + s8;
      f32x4 acc[6];
#pragma unroll
      for (int tt = 0; tt < 6; ++tt) acc[tt] = (f32x4){0.f, 0.f, 0.f, 0.f};
      mfma48(&hb[s & 1][0], g4, wf, acc);
      if (act) {
        float aR = g4 ? acc[1][0] : acc[0][0];
        float aZ = g4 ? acc[3][0] : acc[2][0];
        float aN = g4 ? acc[5][0] : acc[4][0];
        float r    = sigm(xr[s8] + aR + bR);
        float z    = sigm(xz[s8] + aZ + bZ);
        float n    = tanh_fast(xn[s8] + r * (aN + bN));
        float hnew = n + z * (hprev - n);
        hprev = hnew;
        ((half_t*)&hb[(s + 1) & 1][0])[idx] = (half_t)hnew;   // next step's input
        if (hseq) hseq[((size_t)chain * seg + s) * HH + idx] = (half_t)hnew;
        else      outp[((size_t)chain * TT + t0 + s) * HH + idx] = hnew;
      }
      barrier_lds();   // h_{s+1} visible; global stores stay in flight
    }
  }
  if (act) carry[chain * HH + idx] = hprev;
}

// ---------- host ----------
extern "C" void kernel_launch(void* const* d_in, const int* in_sizes, int n_in,
                              void* d_out, int out_size, void* d_ws, size_t ws_size,
                              hipStream_t stream) {
  const float* x   = (const float*)d_in[0];
  const float* Wih = (const float*)d_in[1];
  const float* Whh = (const float*)d_in[2];
  const float* bih = (const float*)d_in[3];
  const float* bhh = (const float*)d_in[4];
  float* outp = (float*)d_out;

  const size_t CARRY = (size_t)2 * BB * HH * sizeof(float);   // both layers
  int seg = 0; bool xf = true;
  {
    const int cand[6] = {2048, 1024, 512, 256, 128, 64};
    for (int ci = 0; ci < 6; ++ci) {
      size_t s = (size_t)cand[ci];
      if (CARRY + s * BB * HH * 2 + s * BB * G3 * 4 <= ws_size) { seg = cand[ci]; xf = true; break; }
    }
    if (!seg) {
      const int cand2[7] = {2048, 1024, 512, 256, 128, 64, 32};
      for (int ci = 0; ci < 7; ++ci) {
        size_t s = (size_t)cand2[ci];
        if (CARRY + s * BB * HH * 2 + s * BB * G3 * 2 <= ws_size) { seg = cand2[ci]; xf = false; break; }
      }
    }
    if (!seg) { seg = 32; xf = false; }   // last resort
  }

  uint8_t* wsb  = (uint8_t*)d_ws;
  float*  carry = (float*)wsb;                       // [2][BB][HH]
  half_t* hseg  = (half_t*)(wsb + CARRY);            // [BB][seg][HH]
  void*   xgs   = wsb + CARRY + (size_t)BB * seg * HH * 2;  // [BB][seg][G3]

  hipMemsetAsync(d_ws, 0, CARRY, stream);            // zero hidden-state carries

  const int tbs = (seg < TBS) ? seg : TBS;
  dim3 ggrid(32 * (seg / tbs));

  for (int t0 = 0; t0 < TT; t0 += seg) {
    if (xf) {
      hipLaunchKernelGGL(HIP_KERNEL_NAME(g_xg<float>), ggrid, dim3(512), 0, stream,
                         x, (const half_t*)nullptr, Wih, bih, (float*)xgs, t0, seg, tbs);
      hipLaunchKernelGGL(HIP_KERNEL_NAME(r_cell<float>), dim3(32), dim3(512), 0, stream,
                         (const float*)xgs, Whh, bhh, hseg, (float*)nullptr, carry, t0, seg);
      hipLaunchKernelGGL(HIP_KERNEL_NAME(g_xg<float>), ggrid, dim3(512), 0, stream,
                         (const float*)nullptr, hseg, Wih + G3 * HH, bih + G3,
                         (float*)xgs, t0, seg, tbs);
      hipLaunchKernelGGL(HIP_KERNEL_NAME(r_cell<float>), dim3(32), dim3(512), 0, stream,
                         (const float*)xgs, Whh + G3 * HH, bhh + G3,
                         (half_t*)nullptr, outp, carry + BB * HH, t0, seg);
    } else {
      hipLaunchKernelGGL(HIP_KERNEL_NAME(g_xg<half_t>), ggrid, dim3(512), 0, stream,
                         x, (const half_t*)nullptr, Wih, bih, (half_t*)xgs, t0, seg, tbs);
      hipLaunchKernelGGL(HIP_KERNEL_NAME(r_cell<half_t>), dim3(32), dim3(512), 0, stream,
                         (const half_t*)xgs, Whh, bhh, hseg, (float*)nullptr, carry, t0, seg);
      hipLaunchKernelGGL(HIP_KERNEL_NAME(g_xg<half_t>), ggrid, dim3(512), 0, stream,
                         (const float*)nullptr, hseg, Wih + G3 * HH, bih + G3,
                         (half_t*)xgs, t0, seg, tbs);
      hipLaunchKernelGGL(HIP_KERNEL_NAME(r_cell<half_t>), dim3(32), dim3(512), 0, stream,
                         (const half_t*)xgs, Whh + G3 * HH, bhh + G3,
                         (half_t*)nullptr, outp, carry + BB * HH, t0, seg);
    }
  }
}